// Round 5
// baseline (184.165 us; speedup 1.0000x reference)
//
#include <hip/hip_runtime.h>

// a,p,n: [16,3,512,512] f32. H=W=512; window 128x128 stride 64 ->
// 8x8 grid of 64x64 base blocks per (b,c) image.
#define WW 512
#define IMG_F 262144            // 512*512 floats per (b,c)
#define NWG 3072                // 48 images * 64 base blocks
#define TOTAL_PIX 12582912.0f   // 16*3*512*512

typedef float f32x4 __attribute__((ext_vector_type(4)));

// Fused kernel: 3072 WGs x 256 threads. Each WG computes one 64x64 base
// block's sums of |n-a| and |a-p| (12 nontemporal float4 loads/thread).
// Last-finishing WG (device-scope counter) runs the tiny finalize with its
// 4 waves -> no second kernel launch, no inter-kernel gap.
__global__ __launch_bounds__(256) void hd_fused(
    const float* __restrict__ a, const float* __restrict__ p,
    const float* __restrict__ n,
    float* __restrict__ blk_na, float* __restrict__ blk_ap,
    unsigned int* __restrict__ counter, float* __restrict__ out)
{
    const int gb  = blockIdx.x;       // 0..3071
    const int bc  = gb >> 6;
    const int blk = gb & 63;
    const int bi = blk >> 3, bj = blk & 7;
    const int tid  = threadIdx.x;
    const int wave = tid >> 6, lane = tid & 63;

    // thread t, step k: row = bi*64 + (t>>4) + 16k, col = bj*64 + (t&15)*4
    const size_t idx0 = (size_t)bc * IMG_F
                      + (size_t)(bi * 64 + (tid >> 4)) * WW
                      + (size_t)(bj * 64 + ((tid & 15) << 2));
    const f32x4* pa = (const f32x4*)(a + idx0);   // row step 16 rows = 2048 float4
    const f32x4* pp = (const f32x4*)(p + idx0);
    const f32x4* pn = (const f32x4*)(n + idx0);

    f32x4 va0 = __builtin_nontemporal_load(pa);
    f32x4 va1 = __builtin_nontemporal_load(pa + 2048);
    f32x4 va2 = __builtin_nontemporal_load(pa + 4096);
    f32x4 va3 = __builtin_nontemporal_load(pa + 6144);
    f32x4 vn0 = __builtin_nontemporal_load(pn);
    f32x4 vn1 = __builtin_nontemporal_load(pn + 2048);
    f32x4 vn2 = __builtin_nontemporal_load(pn + 4096);
    f32x4 vn3 = __builtin_nontemporal_load(pn + 6144);
    f32x4 vp0 = __builtin_nontemporal_load(pp);
    f32x4 vp1 = __builtin_nontemporal_load(pp + 2048);
    f32x4 vp2 = __builtin_nontemporal_load(pp + 4096);
    f32x4 vp3 = __builtin_nontemporal_load(pp + 6144);

    float s1, s2;
    s1  = fabsf(vn0.x - va0.x) + fabsf(vn0.y - va0.y) + fabsf(vn0.z - va0.z) + fabsf(vn0.w - va0.w);
    s1 += fabsf(vn1.x - va1.x) + fabsf(vn1.y - va1.y) + fabsf(vn1.z - va1.z) + fabsf(vn1.w - va1.w);
    s1 += fabsf(vn2.x - va2.x) + fabsf(vn2.y - va2.y) + fabsf(vn2.z - va2.z) + fabsf(vn2.w - va2.w);
    s1 += fabsf(vn3.x - va3.x) + fabsf(vn3.y - va3.y) + fabsf(vn3.z - va3.z) + fabsf(vn3.w - va3.w);
    s2  = fabsf(va0.x - vp0.x) + fabsf(va0.y - vp0.y) + fabsf(va0.z - vp0.z) + fabsf(va0.w - vp0.w);
    s2 += fabsf(va1.x - vp1.x) + fabsf(va1.y - vp1.y) + fabsf(va1.z - vp1.z) + fabsf(va1.w - vp1.w);
    s2 += fabsf(va2.x - vp2.x) + fabsf(va2.y - vp2.y) + fabsf(va2.z - vp2.z) + fabsf(va2.w - vp2.w);
    s2 += fabsf(va3.x - vp3.x) + fabsf(va3.y - vp3.y) + fabsf(va3.z - vp3.z) + fabsf(va3.w - vp3.w);

    #pragma unroll
    for (int off = 32; off > 0; off >>= 1) {
        s1 += __shfl_xor(s1, off, 64);
        s2 += __shfl_xor(s2, off, 64);
    }
    __shared__ float r1[4], r2[4];
    __shared__ int sdone;
    if (lane == 0) { r1[wave] = s1; r2[wave] = s2; }
    __syncthreads();
    if (tid == 0) {
        blk_na[gb] = r1[0] + r1[1] + r1[2] + r1[3];
        blk_ap[gb] = r2[0] + r2[1] + r2[2] + r2[3];
        __threadfence();                       // release partials (device scope)
        unsigned prev = atomicAdd(counter, 1u);
        sdone = (prev == NWG - 1u) ? 1 : 0;
    }
    __syncthreads();
    if (!sdone) return;

    // ---- last WG: finalize (4 waves x 12 images) ----
    __threadfence();                           // acquire all partials

    const int i = lane >> 3, j = lane & 7;
    float acc = 0.f;
    #pragma unroll
    for (int it = 0; it < 12; ++it) {
        const int ibc = it * 4 + wave;
        float b  = blk_na[ibc * 64 + lane];
        float bp = blk_ap[ibc * 64 + lane];
        // diff = sum over 8x8 grid
        float d = b;
        #pragma unroll
        for (int off = 32; off > 0; off >>= 1) d += __shfl_xor(d, off, 64);
        // window value wv[i][j], defined for i,j<7 (else 0)
        float b_r  = __shfl(b, lane + 8, 64);   // blk[i+1][j]
        float b_c  = __shfl(b, lane + 1, 64);   // blk[i][j+1]
        float b_rc = __shfl(b, lane + 9, 64);   // blk[i+1][j+1]
        float wv = (i < 7 && j < 7) ? (b + b_r + b_c + b_rc) / d : 0.f;
        // overlap-add: mb[i][j] = wv[i][j] + wv[i-1][j] + wv[i][j-1] + wv[i-1][j-1]
        float wv_u  = __shfl(wv, lane - 8, 64);
        float wv_l  = __shfl(wv, lane - 1, 64);
        float wv_ul = __shfl(wv, lane - 9, 64);
        float mb = wv;
        if (i > 0)          mb += wv_u;
        if (j > 0)          mb += wv_l;
        if (i > 0 && j > 0) mb += wv_ul;
        const int ci = (i == 0 || i == 7) ? 1 : 2;
        const int cj = (j == 0 || j == 7) ? 1 : 2;
        acc += (mb / (float)(ci * cj)) * bp;
    }

    #pragma unroll
    for (int off = 32; off > 0; off >>= 1) acc += __shfl_xor(acc, off, 64);
    __shared__ float partial[4];
    if (lane == 0) partial[wave] = acc;
    __syncthreads();
    if (tid == 0)
        out[0] = (partial[0] + partial[1] + partial[2] + partial[3]) / TOTAL_PIX;
}

extern "C" void kernel_launch(void* const* d_in, const int* in_sizes, int n_in,
                              void* d_out, int out_size, void* d_ws, size_t ws_size,
                              hipStream_t stream) {
    const float* a = (const float*)d_in[0];
    const float* p = (const float*)d_in[1];
    const float* n = (const float*)d_in[2];
    float* blk_na = (float*)d_ws;                          // 3072 floats
    float* blk_ap = blk_na + NWG;                          // 3072 floats
    unsigned int* counter = (unsigned int*)(blk_ap + NWG); // 1 uint, zeroed below

    (void)hipMemsetAsync((void*)counter, 0, sizeof(unsigned int), stream);
    hd_fused<<<NWG, 256, 0, stream>>>(a, p, n, blk_na, blk_ap, counter, (float*)d_out);
}

// Round 6
// 60.374 us; speedup vs baseline: 3.0504x; 3.0504x over previous
//
#include <hip/hip_runtime.h>

// a,p,n: [16,3,512,512] f32. H=W=512; window 128x128 stride 64 ->
// 8x8 grid of 64x64 base blocks per (b,c) image.
#define WW 512
#define IMG_F 262144            // 512*512 floats per (b,c)
#define NWG 3072                // 48 images * 64 base blocks
#define TOTAL_PIX 12582912.0f   // 16*3*512*512

// Fused kernel: 3072 WGs x 256 threads. Each WG computes one 64x64 base
// block's sums of |n-a| and |a-p| (12 float4 loads/thread). Partials are
// published with device-scope atomicExch (coherence-point writes -> no
// L2-writeback fence needed); a wave-local vmcnt(0) orders them before the
// counter bump. Only the single last WG pays a full __threadfence (acquire)
// before reading all partials and computing the loss.
__global__ __launch_bounds__(256) void hd_fused(
    const float* __restrict__ a, const float* __restrict__ p,
    const float* __restrict__ n,
    float* __restrict__ blk_na, float* __restrict__ blk_ap,
    unsigned int* __restrict__ counter, float* __restrict__ out)
{
    const int gb  = blockIdx.x;       // 0..3071
    const int bc  = gb >> 6;
    const int blk = gb & 63;
    const int bi = blk >> 3, bj = blk & 7;
    const int tid  = threadIdx.x;
    const int wave = tid >> 6, lane = tid & 63;

    // thread t, step k: row = bi*64 + (t>>4) + 16k, col = bj*64 + (t&15)*4
    const size_t idx0 = (size_t)bc * IMG_F
                      + (size_t)(bi * 64 + (tid >> 4)) * WW
                      + (size_t)(bj * 64 + ((tid & 15) << 2));
    const float4* pa = (const float4*)(a + idx0);   // row step 16 rows = 2048 float4
    const float4* pp = (const float4*)(p + idx0);
    const float4* pn = (const float4*)(n + idx0);

    float4 va0 = pa[0], va1 = pa[2048], va2 = pa[4096], va3 = pa[6144];
    float4 vn0 = pn[0], vn1 = pn[2048], vn2 = pn[4096], vn3 = pn[6144];
    float4 vp0 = pp[0], vp1 = pp[2048], vp2 = pp[4096], vp3 = pp[6144];

    float s1, s2;
    s1  = fabsf(vn0.x - va0.x) + fabsf(vn0.y - va0.y) + fabsf(vn0.z - va0.z) + fabsf(vn0.w - va0.w);
    s1 += fabsf(vn1.x - va1.x) + fabsf(vn1.y - va1.y) + fabsf(vn1.z - va1.z) + fabsf(vn1.w - va1.w);
    s1 += fabsf(vn2.x - va2.x) + fabsf(vn2.y - va2.y) + fabsf(vn2.z - va2.z) + fabsf(vn2.w - va2.w);
    s1 += fabsf(vn3.x - va3.x) + fabsf(vn3.y - va3.y) + fabsf(vn3.z - va3.z) + fabsf(vn3.w - va3.w);
    s2  = fabsf(va0.x - vp0.x) + fabsf(va0.y - vp0.y) + fabsf(va0.z - vp0.z) + fabsf(va0.w - vp0.w);
    s2 += fabsf(va1.x - vp1.x) + fabsf(va1.y - vp1.y) + fabsf(va1.z - vp1.z) + fabsf(va1.w - vp1.w);
    s2 += fabsf(va2.x - vp2.x) + fabsf(va2.y - vp2.y) + fabsf(va2.z - vp2.z) + fabsf(va2.w - vp2.w);
    s2 += fabsf(va3.x - vp3.x) + fabsf(va3.y - vp3.y) + fabsf(va3.z - vp3.z) + fabsf(va3.w - vp3.w);

    #pragma unroll
    for (int off = 32; off > 0; off >>= 1) {
        s1 += __shfl_xor(s1, off, 64);
        s2 += __shfl_xor(s2, off, 64);
    }
    __shared__ float r1[4], r2[4];
    __shared__ int sdone;
    if (lane == 0) { r1[wave] = s1; r2[wave] = s2; }
    __syncthreads();
    if (tid == 0) {
        // Publish partials at the coherence point (device-scope atomics);
        // no L2 writeback fence needed since no dirty cached copy exists.
        atomicExch(&blk_na[gb], r1[0] + r1[1] + r1[2] + r1[3]);
        atomicExch(&blk_ap[gb], r2[0] + r2[1] + r2[2] + r2[3]);
        // Order: both exchs complete before the counter bump is issued.
        asm volatile("s_waitcnt vmcnt(0)" ::: "memory");
        unsigned prev = atomicAdd(counter, 1u);
        sdone = (prev == NWG - 1u) ? 1 : 0;
    }
    __syncthreads();
    if (!sdone) return;

    // ---- last WG only: finalize (4 waves x 12 images) ----
    __threadfence();                           // acquire: invalidate stale lines

    const int i = lane >> 3, j = lane & 7;
    float acc = 0.f;
    #pragma unroll
    for (int it = 0; it < 12; ++it) {
        const int ibc = it * 4 + wave;
        float b  = blk_na[ibc * 64 + lane];
        float bp = blk_ap[ibc * 64 + lane];
        // diff = sum over 8x8 grid
        float d = b;
        #pragma unroll
        for (int off = 32; off > 0; off >>= 1) d += __shfl_xor(d, off, 64);
        // window value wv[i][j], defined for i,j<7 (else 0)
        float b_r  = __shfl(b, lane + 8, 64);   // blk[i+1][j]
        float b_c  = __shfl(b, lane + 1, 64);   // blk[i][j+1]
        float b_rc = __shfl(b, lane + 9, 64);   // blk[i+1][j+1]
        float wv = (i < 7 && j < 7) ? (b + b_r + b_c + b_rc) / d : 0.f;
        // overlap-add: mb[i][j] = wv[i][j] + wv[i-1][j] + wv[i][j-1] + wv[i-1][j-1]
        float wv_u  = __shfl(wv, lane - 8, 64);
        float wv_l  = __shfl(wv, lane - 1, 64);
        float wv_ul = __shfl(wv, lane - 9, 64);
        float mb = wv;
        if (i > 0)          mb += wv_u;
        if (j > 0)          mb += wv_l;
        if (i > 0 && j > 0) mb += wv_ul;
        const int ci = (i == 0 || i == 7) ? 1 : 2;
        const int cj = (j == 0 || j == 7) ? 1 : 2;
        acc += (mb / (float)(ci * cj)) * bp;
    }

    #pragma unroll
    for (int off = 32; off > 0; off >>= 1) acc += __shfl_xor(acc, off, 64);
    __shared__ float partial[4];
    if (lane == 0) partial[wave] = acc;
    __syncthreads();
    if (tid == 0)
        out[0] = (partial[0] + partial[1] + partial[2] + partial[3]) / TOTAL_PIX;
}

extern "C" void kernel_launch(void* const* d_in, const int* in_sizes, int n_in,
                              void* d_out, int out_size, void* d_ws, size_t ws_size,
                              hipStream_t stream) {
    const float* a = (const float*)d_in[0];
    const float* p = (const float*)d_in[1];
    const float* n = (const float*)d_in[2];
    float* blk_na = (float*)d_ws;                          // 3072 floats
    float* blk_ap = blk_na + NWG;                          // 3072 floats
    unsigned int* counter = (unsigned int*)(blk_ap + NWG); // 1 uint

    (void)hipMemsetAsync((void*)counter, 0, sizeof(unsigned int), stream);
    hd_fused<<<NWG, 256, 0, stream>>>(a, p, n, blk_na, blk_ap, counter, (float*)d_out);
}

// Round 7
// 51.696 us; speedup vs baseline: 3.5625x; 1.1679x over previous
//
#include <hip/hip_runtime.h>

// a,p,n: [16,3,512,512] f32. H=W=512; window 128x128 stride 64 ->
// 8x8 grid of 64x64 base blocks per (b,c) image.
#define WW 512
#define IMG_F 262144            // 512*512 floats per (b,c)
#define BC 48                   // 16*3 images
#define NWG 3072                // 48 images * 64 base blocks
#define TOTAL_PIX 12582912.0f   // 16*3*512*512

// Fused kernel, hierarchical completion:
//   stage 1 (all 3072 WGs): 64x64 block sums of |n-a|,|a-p|; publish via
//     device-scope atomicExch (coherence-point write, no fence), bump
//     img_cnt[bc] (48 parallel counters -> negligible serialization).
//   stage 2 (last WG of each image, wave 0): agent-scope atomic loads of the
//     image's 64 block partials, shuffle math -> per-image loss contribution;
//     publish, bump done_cnt (only 48 same-address atomics).
//   stage 3 (last image, wave 0): sum 48 scalars, write out.
__global__ __launch_bounds__(256) void hd_fused(
    const float* __restrict__ a, const float* __restrict__ p,
    const float* __restrict__ n,
    float* __restrict__ blk_na, float* __restrict__ blk_ap,
    float* __restrict__ img_loss, unsigned int* __restrict__ img_cnt,
    unsigned int* __restrict__ done_cnt, float* __restrict__ out)
{
    const int gb  = blockIdx.x;       // 0..3071
    const int bc  = gb >> 6;
    const int blk = gb & 63;
    const int bi = blk >> 3, bj = blk & 7;
    const int tid  = threadIdx.x;
    const int wave = tid >> 6, lane = tid & 63;

    // thread t, step k: row = bi*64 + (t>>4) + 16k, col = bj*64 + (t&15)*4
    const size_t idx0 = (size_t)bc * IMG_F
                      + (size_t)(bi * 64 + (tid >> 4)) * WW
                      + (size_t)(bj * 64 + ((tid & 15) << 2));
    const float4* pa = (const float4*)(a + idx0);   // 16-row step = 2048 float4
    const float4* pp = (const float4*)(p + idx0);
    const float4* pn = (const float4*)(n + idx0);

    float4 va0 = pa[0], va1 = pa[2048], va2 = pa[4096], va3 = pa[6144];
    float4 vn0 = pn[0], vn1 = pn[2048], vn2 = pn[4096], vn3 = pn[6144];
    float4 vp0 = pp[0], vp1 = pp[2048], vp2 = pp[4096], vp3 = pp[6144];

    float s1, s2;
    s1  = fabsf(vn0.x - va0.x) + fabsf(vn0.y - va0.y) + fabsf(vn0.z - va0.z) + fabsf(vn0.w - va0.w);
    s1 += fabsf(vn1.x - va1.x) + fabsf(vn1.y - va1.y) + fabsf(vn1.z - va1.z) + fabsf(vn1.w - va1.w);
    s1 += fabsf(vn2.x - va2.x) + fabsf(vn2.y - va2.y) + fabsf(vn2.z - va2.z) + fabsf(vn2.w - va2.w);
    s1 += fabsf(vn3.x - va3.x) + fabsf(vn3.y - va3.y) + fabsf(vn3.z - va3.z) + fabsf(vn3.w - va3.w);
    s2  = fabsf(va0.x - vp0.x) + fabsf(va0.y - vp0.y) + fabsf(va0.z - vp0.z) + fabsf(va0.w - vp0.w);
    s2 += fabsf(va1.x - vp1.x) + fabsf(va1.y - vp1.y) + fabsf(va1.z - vp1.z) + fabsf(va1.w - vp1.w);
    s2 += fabsf(va2.x - vp2.x) + fabsf(va2.y - vp2.y) + fabsf(va2.z - vp2.z) + fabsf(va2.w - vp2.w);
    s2 += fabsf(va3.x - vp3.x) + fabsf(va3.y - vp3.y) + fabsf(va3.z - vp3.z) + fabsf(va3.w - vp3.w);

    #pragma unroll
    for (int off = 32; off > 0; off >>= 1) {
        s1 += __shfl_xor(s1, off, 64);
        s2 += __shfl_xor(s2, off, 64);
    }
    __shared__ float r1[4], r2[4];
    __shared__ int sdone;
    if (lane == 0) { r1[wave] = s1; r2[wave] = s2; }
    __syncthreads();
    if (tid == 0) {
        // Coherence-point publishes; no L2-writeback fence needed.
        atomicExch(&blk_na[gb], r1[0] + r1[1] + r1[2] + r1[3]);
        atomicExch(&blk_ap[gb], r2[0] + r2[1] + r2[2] + r2[3]);
        asm volatile("s_waitcnt vmcnt(0)" ::: "memory");  // exchs done first
        unsigned prev = atomicAdd(&img_cnt[bc], 1u);
        sdone = (prev == 63u) ? 1 : 0;
    }
    __syncthreads();                  // last barrier; safe divergent exits below
    if (!sdone || wave != 0) return;

    // ---- stage 2: wave 0 of this image's last WG finalizes image bc ----
    const int i = lane >> 3, j = lane & 7;
    float b  = __hip_atomic_load(&blk_na[bc * 64 + lane], __ATOMIC_RELAXED, __HIP_MEMORY_SCOPE_AGENT);
    float bp = __hip_atomic_load(&blk_ap[bc * 64 + lane], __ATOMIC_RELAXED, __HIP_MEMORY_SCOPE_AGENT);
    // diff = sum over 8x8 grid
    float d = b;
    #pragma unroll
    for (int off = 32; off > 0; off >>= 1) d += __shfl_xor(d, off, 64);
    // window value wv[i][j], defined for i,j<7 (else 0)
    float b_r  = __shfl(b, lane + 8, 64);   // blk[i+1][j]
    float b_c  = __shfl(b, lane + 1, 64);   // blk[i][j+1]
    float b_rc = __shfl(b, lane + 9, 64);   // blk[i+1][j+1]
    float wv = (i < 7 && j < 7) ? (b + b_r + b_c + b_rc) / d : 0.f;
    // overlap-add: mb[i][j] = wv[i][j] + wv[i-1][j] + wv[i][j-1] + wv[i-1][j-1]
    float wv_u  = __shfl(wv, lane - 8, 64);
    float wv_l  = __shfl(wv, lane - 1, 64);
    float wv_ul = __shfl(wv, lane - 9, 64);
    float mb = wv;
    if (i > 0)          mb += wv_u;
    if (j > 0)          mb += wv_l;
    if (i > 0 && j > 0) mb += wv_ul;
    const int ci = (i == 0 || i == 7) ? 1 : 2;
    const int cj = (j == 0 || j == 7) ? 1 : 2;
    float acc = (mb / (float)(ci * cj)) * bp;
    #pragma unroll
    for (int off = 32; off > 0; off >>= 1) acc += __shfl_xor(acc, off, 64);

    int last = 0;
    if (lane == 0) {
        atomicExch(&img_loss[bc], acc);
        asm volatile("s_waitcnt vmcnt(0)" ::: "memory");
        last = (atomicAdd(done_cnt, 1u) == BC - 1u) ? 1 : 0;
    }
    last = __shfl(last, 0, 64);
    if (!last) return;

    // ---- stage 3: global last wave sums the 48 per-image scalars ----
    float v = (lane < BC)
        ? __hip_atomic_load(&img_loss[lane], __ATOMIC_RELAXED, __HIP_MEMORY_SCOPE_AGENT)
        : 0.f;
    #pragma unroll
    for (int off = 32; off > 0; off >>= 1) v += __shfl_xor(v, off, 64);
    if (lane == 0) out[0] = v / TOTAL_PIX;
}

extern "C" void kernel_launch(void* const* d_in, const int* in_sizes, int n_in,
                              void* d_out, int out_size, void* d_ws, size_t ws_size,
                              hipStream_t stream) {
    const float* a = (const float*)d_in[0];
    const float* p = (const float*)d_in[1];
    const float* n = (const float*)d_in[2];
    float* blk_na = (float*)d_ws;                       // 3072
    float* blk_ap = blk_na + NWG;                       // 3072
    float* img_loss = blk_ap + NWG;                     // 48
    unsigned int* img_cnt = (unsigned int*)(img_loss + BC);  // 48
    unsigned int* done_cnt = img_cnt + BC;                   // 1

    // zero the 49 counters (poison-safe, graph-capturable)
    (void)hipMemsetAsync((void*)img_cnt, 0, (BC + 1) * sizeof(unsigned int), stream);
    hd_fused<<<NWG, 256, 0, stream>>>(a, p, n, blk_na, blk_ap,
                                      img_loss, img_cnt, done_cnt, (float*)d_out);
}

// Round 8
// 31.274 us; speedup vs baseline: 5.8888x; 1.6530x over previous
//
#include <hip/hip_runtime.h>

// a,p,n: [16,3,512,512] f32. H=W=512; window 128x128 stride 64 ->
// 8x8 grid of 64x64 base blocks per (b,c) image.
#define WW 512
#define IMG_F 262144            // 512*512 floats per (b,c)
#define NWG 3072                // 48 images * 64 base blocks
#define TOTAL_PIX 12582912.0f   // 16*3*512*512

// Kernel 1: per-base-block sums of |n-a| (x) and |a-p| (y), packed float2.
// grid = 3072 WGs x 256 threads, 12 float4 loads per thread.
__global__ __launch_bounds__(256) void hd_block_sums(
    const float* __restrict__ a, const float* __restrict__ p,
    const float* __restrict__ n, float2* __restrict__ blk)
{
    const int gb  = blockIdx.x;       // 0..3071
    const int bc  = gb >> 6;
    const int blkid = gb & 63;
    const int bi = blkid >> 3, bj = blkid & 7;
    const int tid = threadIdx.x;

    // thread t, step k: row = bi*64 + (t>>4) + 16k, col = bj*64 + (t&15)*4
    const size_t idx0 = (size_t)bc * IMG_F
                      + (size_t)(bi * 64 + (tid >> 4)) * WW
                      + (size_t)(bj * 64 + ((tid & 15) << 2));
    const float4* pa = (const float4*)(a + idx0);   // 16-row step = 2048 float4
    const float4* pp = (const float4*)(p + idx0);
    const float4* pn = (const float4*)(n + idx0);

    float4 va0 = pa[0], va1 = pa[2048], va2 = pa[4096], va3 = pa[6144];
    float4 vn0 = pn[0], vn1 = pn[2048], vn2 = pn[4096], vn3 = pn[6144];
    float4 vp0 = pp[0], vp1 = pp[2048], vp2 = pp[4096], vp3 = pp[6144];

    float s1, s2;
    s1  = fabsf(vn0.x - va0.x) + fabsf(vn0.y - va0.y) + fabsf(vn0.z - va0.z) + fabsf(vn0.w - va0.w);
    s1 += fabsf(vn1.x - va1.x) + fabsf(vn1.y - va1.y) + fabsf(vn1.z - va1.z) + fabsf(vn1.w - va1.w);
    s1 += fabsf(vn2.x - va2.x) + fabsf(vn2.y - va2.y) + fabsf(vn2.z - va2.z) + fabsf(vn2.w - va2.w);
    s1 += fabsf(vn3.x - va3.x) + fabsf(vn3.y - va3.y) + fabsf(vn3.z - va3.z) + fabsf(vn3.w - va3.w);
    s2  = fabsf(va0.x - vp0.x) + fabsf(va0.y - vp0.y) + fabsf(va0.z - vp0.z) + fabsf(va0.w - vp0.w);
    s2 += fabsf(va1.x - vp1.x) + fabsf(va1.y - vp1.y) + fabsf(va1.z - vp1.z) + fabsf(va1.w - vp1.w);
    s2 += fabsf(va2.x - vp2.x) + fabsf(va2.y - vp2.y) + fabsf(va2.z - vp2.z) + fabsf(va2.w - vp2.w);
    s2 += fabsf(va3.x - vp3.x) + fabsf(va3.y - vp3.y) + fabsf(va3.z - vp3.z) + fabsf(va3.w - vp3.w);

    #pragma unroll
    for (int off = 32; off > 0; off >>= 1) {
        s1 += __shfl_xor(s1, off, 64);
        s2 += __shfl_xor(s2, off, 64);
    }
    __shared__ float r1[4], r2[4];
    const int wave = tid >> 6, lane = tid & 63;
    if (lane == 0) { r1[wave] = s1; r2[wave] = s2; }
    __syncthreads();
    if (tid == 0)
        blk[gb] = make_float2(r1[0] + r1[1] + r1[2] + r1[3],
                              r2[0] + r2[1] + r2[2] + r2[3]);
}

// Kernel 2: finalize. One wave per (b,c); 64 lanes = the 8x8 block grid.
// All 3 images' partials loaded up-front (3 independent float2 loads/lane),
// then pure shuffle math. 1 block x 1024 threads, 16 waves x 3 images.
__global__ __launch_bounds__(1024) void hd_finalize(
    const float2* __restrict__ blk, float* __restrict__ out)
{
    const int tid  = threadIdx.x;
    const int w    = tid >> 6;        // wave 0..15
    const int lane = tid & 63;
    const int i = lane >> 3, j = lane & 7;
    __shared__ float partial[16];

    // issue all loads first (hide latency once)
    float2 q0 = blk[(w     ) * 64 + lane];
    float2 q1 = blk[(w + 16) * 64 + lane];
    float2 q2 = blk[(w + 32) * 64 + lane];

    float acc = 0.f;
    #pragma unroll
    for (int it = 0; it < 3; ++it) {
        float b  = (it == 0) ? q0.x : (it == 1) ? q1.x : q2.x;
        float bp = (it == 0) ? q0.y : (it == 1) ? q1.y : q2.y;
        // diff = sum over 8x8 grid
        float d = b;
        #pragma unroll
        for (int off = 32; off > 0; off >>= 1) d += __shfl_xor(d, off, 64);
        // window value wv[i][j], defined for i,j<7 (else 0)
        float b_r  = __shfl(b, lane + 8, 64);   // blk[i+1][j]
        float b_c  = __shfl(b, lane + 1, 64);   // blk[i][j+1]
        float b_rc = __shfl(b, lane + 9, 64);   // blk[i+1][j+1]
        float wv = (i < 7 && j < 7) ? (b + b_r + b_c + b_rc) / d : 0.f;
        // overlap-add: mb[i][j] = wv[i][j] + wv[i-1][j] + wv[i][j-1] + wv[i-1][j-1]
        float wv_u  = __shfl(wv, lane - 8, 64);
        float wv_l  = __shfl(wv, lane - 1, 64);
        float wv_ul = __shfl(wv, lane - 9, 64);
        float mb = wv;
        if (i > 0)          mb += wv_u;
        if (j > 0)          mb += wv_l;
        if (i > 0 && j > 0) mb += wv_ul;
        const int ci = (i == 0 || i == 7) ? 1 : 2;
        const int cj = (j == 0 || j == 7) ? 1 : 2;
        acc += (mb / (float)(ci * cj)) * bp;
    }

    #pragma unroll
    for (int off = 32; off > 0; off >>= 1) acc += __shfl_xor(acc, off, 64);
    if (lane == 0) partial[w] = acc;
    __syncthreads();
    if (tid == 0) {
        float s = 0.f;
        #pragma unroll
        for (int k = 0; k < 16; ++k) s += partial[k];
        out[0] = s / TOTAL_PIX;
    }
}

extern "C" void kernel_launch(void* const* d_in, const int* in_sizes, int n_in,
                              void* d_out, int out_size, void* d_ws, size_t ws_size,
                              hipStream_t stream) {
    const float* a = (const float*)d_in[0];
    const float* p = (const float*)d_in[1];
    const float* n = (const float*)d_in[2];
    float2* blk = (float2*)d_ws;                  // 3072 float2

    hd_block_sums<<<NWG, 256, 0, stream>>>(a, p, n, blk);
    hd_finalize<<<1, 1024, 0, stream>>>(blk, (float*)d_out);
}